// Round 1
// baseline (580.051 us; speedup 1.0000x reference)
//
#include <hip/hip_runtime.h>
#include <stdint.h>

#define N_ROWS 131072
#define D_IN   512
#define D_OUT  512
#define BM     64
#define THREADS 512
#define LDA    520                    // padded bf16 row stride (1040 B = 65*16, stride ≡ 4 mod 32 dwords)
#define LDS_BYTES (BM * LDA * 2)      // 66560 B -> 2 blocks/CU (160 KB limit)

typedef short  s8v __attribute__((ext_vector_type(8)));   // 8 bf16 bits (4 VGPRs)
typedef float  f4v __attribute__((ext_vector_type(4)));   // MFMA acc
typedef unsigned int u32;

// fp32 -> bf16 bits, round-to-nearest-even
__device__ __forceinline__ unsigned short f2bf(float f) {
    u32 b = __builtin_bit_cast(u32, f);
    b += 0x7FFFu + ((b >> 16) & 1u);
    return (unsigned short)(b >> 16);
}

// ---------------------------------------------------------------------------
// W fp32 [k][n] -> Wb bf16 [n][k] (plain transpose). 512 KB, fully L2-resident;
// B fragments are read straight from global in the GEMM (no LDS staging).
// ---------------------------------------------------------------------------
__global__ void convert_w(const float* __restrict__ W, unsigned short* __restrict__ wb) {
    int t = blockIdx.x * blockDim.x + threadIdx.x;   // 0 .. 262143
    int k = t & 511;
    int n = t >> 9;
    wb[t] = f2bf(W[k * 512 + n]);                    // wb[n*512 + k]
}

// ---------------------------------------------------------------------------
// y = x @ W + b.  BM=64 rows/block, BN=512 (full D_OUT -> X read exactly once).
// A: whole 64x512 tile staged ONCE in LDS as bf16 (padded rows, 2-way=free reads).
// B: direct global 16B fragment loads from L2-resident Wb, depth-1 reg prefetch.
// NO barriers in the main loop; occupancy 2 blocks/CU = 16 waves.
// Wave wv owns cols [wv*64, wv*64+64); 4x4 frags of 16x16x32 bf16 MFMA.
// ---------------------------------------------------------------------------
__global__ __launch_bounds__(THREADS, 4) void sparse_dense_gemm(
    const float* __restrict__ X, const unsigned short* __restrict__ Wb,
    const float* __restrict__ bias, float* __restrict__ Y)
{
    extern __shared__ char smem[];
    unsigned short* Ash = (unsigned short*)smem;     // [64][520] bf16

    const int tid  = threadIdx.x;
    const int lane = tid & 63;
    const int wv   = tid >> 6;          // 0..7
    const int r0   = blockIdx.x * BM;
    const int c    = lane & 15;         // frag col / row selector
    const int q    = lane >> 4;         // quad 0..3

    // ---- stage A: X[r0..r0+64) x 512 fp32 (one contiguous 128 KB region) -> bf16 LDS ----
    const float4* Xblk = (const float4*)(X + (size_t)r0 * D_IN);
    {
        const int row0 = tid >> 7;           // 0..3
        const int col  = (tid & 127) * 4;    // 0..508
        #pragma unroll
        for (int i = 0; i < 16; ++i) {
            float4 v = Xblk[i * 512 + tid];  // coalesced 16B/lane
            u32 lo = (u32)f2bf(v.x) | ((u32)f2bf(v.y) << 16);
            u32 hi = (u32)f2bf(v.z) | ((u32)f2bf(v.w) << 16);
            *(uint2*)(Ash + (i * 4 + row0) * LDA + col) = make_uint2(lo, hi);
        }
    }

    // ---- per-lane B base: Wb row n = wv*64 + nf*16 + c, k = it*32 + q*8 + j ----
    // One wave instr = 16 n-values x 64B (4 q-lanes contiguous) = 16 fully-used lines.
    const unsigned short* Bp = Wb + (size_t)(wv * 64 + c) * 512 + q * 8;

    f4v acc[4][4];
    #pragma unroll
    for (int mf = 0; mf < 4; ++mf)
        #pragma unroll
        for (int nf = 0; nf < 4; ++nf)
            acc[mf][nf] = f4v{0.f, 0.f, 0.f, 0.f};

    s8v bA[4], bB[4];
    #pragma unroll
    for (int nf = 0; nf < 4; ++nf)      // prologue: it=0 fragments (pre-barrier, independent)
        bA[nf] = *(const s8v*)(Bp + nf * 8192);

    __syncthreads();                    // the ONLY barrier

    const unsigned short* Arow = Ash + c * LDA + q * 8;

    // 16 k-steps (it = kt*2+ks), ping-pong B prefetch one step ahead
    #pragma unroll
    for (int it2 = 0; it2 < 8; ++it2) {
        const int itE = 2 * it2, itO = itE + 1;
        #pragma unroll
        for (int nf = 0; nf < 4; ++nf)
            bB[nf] = *(const s8v*)(Bp + nf * 8192 + itO * 32);
        {
            s8v af[4];
            #pragma unroll
            for (int mf = 0; mf < 4; ++mf)
                af[mf] = *(const s8v*)(Arow + mf * 16 * LDA + itE * 32);
            #pragma unroll
            for (int mf = 0; mf < 4; ++mf)
                #pragma unroll
                for (int nf = 0; nf < 4; ++nf)
                    acc[mf][nf] = __builtin_amdgcn_mfma_f32_16x16x32_bf16(
                        af[mf], bA[nf], acc[mf][nf], 0, 0, 0);
        }
        if (it2 < 7) {
            #pragma unroll
            for (int nf = 0; nf < 4; ++nf)
                bA[nf] = *(const s8v*)(Bp + nf * 8192 + (itE + 2) * 32);
        }
        {
            s8v af[4];
            #pragma unroll
            for (int mf = 0; mf < 4; ++mf)
                af[mf] = *(const s8v*)(Arow + mf * 16 * LDA + itO * 32);
            #pragma unroll
            for (int mf = 0; mf < 4; ++mf)
                #pragma unroll
                for (int nf = 0; nf < 4; ++nf)
                    acc[mf][nf] = __builtin_amdgcn_mfma_f32_16x16x32_bf16(
                        af[mf], bB[nf], acc[mf][nf], 0, 0, 0);
        }
    }

    // ---- epilogue: C/D layout col=lane&15, row=(lane>>4)*4+i (verified mapping) ----
    #pragma unroll
    for (int nf = 0; nf < 4; ++nf) {
        int col = wv * 64 + nf * 16 + c;
        float bv = bias[col];
        #pragma unroll
        for (int mf = 0; mf < 4; ++mf) {
            #pragma unroll
            for (int i = 0; i < 4; ++i) {
                int row = r0 + mf * 16 + q * 4 + i;
                Y[(size_t)row * D_OUT + col] = acc[mf][nf][i] + bv;
            }
        }
    }
}

extern "C" void kernel_launch(void* const* d_in, const int* in_sizes, int n_in,
                              void* d_out, int out_size, void* d_ws, size_t ws_size,
                              hipStream_t stream) {
    const float* X    = (const float*)d_in[0];
    const float* W    = (const float*)d_in[1];
    const float* bias = (const float*)d_in[2];
    float* Y          = (float*)d_out;
    unsigned short* wsb = (unsigned short*)d_ws;   // 512 KB bf16 W^T copy

    (void)hipFuncSetAttribute((const void*)sparse_dense_gemm,
                              hipFuncAttributeMaxDynamicSharedMemorySize, LDS_BYTES);

    convert_w<<<1024, 256, 0, stream>>>(W, wsb);
    sparse_dense_gemm<<<N_ROWS / BM, THREADS, LDS_BYTES, stream>>>(X, wsb, bias, Y);
}

// Round 2
// 479.339 us; speedup vs baseline: 1.2101x; 1.2101x over previous
//
#include <hip/hip_runtime.h>
#include <stdint.h>

#define N_ROWS 131072
#define D_IN   512
#define D_OUT  512
#define BM     64
#define BK     32
#define NKT    (D_IN / BK)            // 16
#define THREADS 512

// LDS: B dbuf 2 x [512][32] bf16 = 64 KB, A dbuf 2 x [64][32] bf16 = 8 KB
// total 73728 B -> 2 blocks/CU (160 KB limit). 64 B row stride => b128 frag
// reads are naturally bank-uniform (16 dwords mod 32 interleave): no swizzle.
#define BTILE  (D_OUT * BK)           // 16384 elems
#define ATILE  (BM * BK)              // 2048 elems
#define LDS_BYTES ((2 * BTILE + 2 * ATILE) * 2)

typedef short  s8v __attribute__((ext_vector_type(8)));   // 8 bf16 bits (4 VGPRs)
typedef float  f4v __attribute__((ext_vector_type(4)));   // MFMA acc
typedef unsigned int u32;

// fp32 -> bf16 bits, round-to-nearest-even (exact for 0.0/1.0 spike inputs)
__device__ __forceinline__ unsigned short f2bf(float f) {
    u32 b = __builtin_bit_cast(u32, f);
    b += 0x7FFFu + ((b >> 16) & 1u);
    return (unsigned short)(b >> 16);
}

// ---------------------------------------------------------------------------
// W fp32 [k][n] -> Wb bf16, k-tiled transpose: Wb[(kt*512 + n)*32 + kk] =
// bf16(W[(kt*32 + kk)*512 + n]). Each 32 KB slab [kt] is the contiguous
// LDS image for that k-tile, so the GEMM fills it with linear global_load_lds.
// ---------------------------------------------------------------------------
__global__ void convert_w(const float* __restrict__ W, unsigned short* __restrict__ wb) {
    int t  = blockIdx.x * blockDim.x + threadIdx.x;   // 0 .. 262143
    int kk = t & 31;
    int n  = (t >> 5) & 511;
    int kt = t >> 14;
    wb[t] = f2bf(W[(kt * 32 + kk) * 512 + n]);
}

// ---------------------------------------------------------------------------
// y = x @ W + b.  BM=64 rows/block, BN=512 (full D_OUT -> X read exactly once),
// BK=32.  512 threads = 8 waves; wave wv owns cols [wv*64, wv*64+64) as 4x4
// frags of 16x16x32 bf16 MFMA.  Double-buffered LDS for A and B; B staged via
// global_load_lds from the L2-resident 512 KB Wb; X loaded as float4, converted
// to bf16 in VALU, ds_write'd.  2 blocks/CU so the per-tile barrier drain of
// one block hides under the other block's compute phase.
// ---------------------------------------------------------------------------
__global__ __launch_bounds__(THREADS, 4) void sparse_dense_gemm(
    const float* __restrict__ X, const unsigned short* __restrict__ Wb,
    const float* __restrict__ bias, float* __restrict__ Y)
{
    extern __shared__ char smem[];
    unsigned short* bufB = (unsigned short*)smem;                    // [2][512*32]
    unsigned short* bufA = (unsigned short*)(smem + 2 * BTILE * 2);  // [2][64*32]

    const int tid  = threadIdx.x;
    const int lane = tid & 63;
    const int wv   = tid >> 6;          // 0..7
    const int r0   = blockIdx.x * BM;
    const int c    = lane & 15;         // frag row/col selector
    const int q    = lane >> 4;         // quad 0..3 -> k-slot q*8..q*8+7

    // A staging map: thread -> (row, float4 k-slot); coalesced 128 B per 8 lanes
    const int arow = tid >> 3;          // 0..63
    const int akd  = tid & 7;           // 0..7
    const float* xsrc = X + (size_t)(r0 + arow) * D_IN + akd * 4;

    auto stageB = [&](int kt, int buf) {
        const unsigned short* src = Wb + (size_t)kt * BTILE;
        unsigned short* dst = bufB + buf * BTILE;
        #pragma unroll
        for (int r = 0; r < 4; ++r) {
            int o = (r * 512 + tid) * 8;   // element offset; x2 B = 16 B/thread, linear
            __builtin_amdgcn_global_load_lds(
                (const __attribute__((address_space(1))) u32*)(src + o),
                (__attribute__((address_space(3)))       u32*)(dst + o),
                16, 0, 0);
        }
    };
    auto writeA = [&](float4 v, int buf) {
        u32 lo = (u32)f2bf(v.x) | ((u32)f2bf(v.y) << 16);
        u32 hi = (u32)f2bf(v.z) | ((u32)f2bf(v.w) << 16);
        *(uint2*)(bufA + buf * ATILE + arow * BK + akd * 4) = make_uint2(lo, hi);
    };

    f4v acc[4][4];
    #pragma unroll
    for (int mf = 0; mf < 4; ++mf)
        #pragma unroll
        for (int nf = 0; nf < 4; ++nf)
            acc[mf][nf] = f4v{0.f, 0.f, 0.f, 0.f};

    // ---- prologue: stage k-tile 0 into buffer 0 ----
    {
        float4 x0 = *(const float4*)(xsrc);
        stageB(0, 0);
        writeA(x0, 0);
    }

    int p = 0;
    #pragma unroll 2
    for (int kt = 0; kt < NKT; ++kt) {
        __syncthreads();               // buffer p staged; buffer p^1 free
        float4 xn;
        if (kt + 1 < NKT) {
            xn = *(const float4*)(xsrc + (kt + 1) * BK);   // HBM load flies over compute
            stageB(kt + 1, p ^ 1);                         // L2->LDS flies over compute
        }

        // ---- compute on buffer p ----
        const unsigned short* Ab = bufA + p * ATILE;
        const unsigned short* Bb = bufB + p * BTILE;
        s8v af[4], bfr[4];
        #pragma unroll
        for (int mf = 0; mf < 4; ++mf)
            af[mf] = *(const s8v*)(Ab + (mf * 16 + c) * BK + q * 8);
        #pragma unroll
        for (int nf = 0; nf < 4; ++nf)
            bfr[nf] = *(const s8v*)(Bb + (wv * 64 + nf * 16 + c) * BK + q * 8);
        #pragma unroll
        for (int mf = 0; mf < 4; ++mf)
            #pragma unroll
            for (int nf = 0; nf < 4; ++nf)
                acc[mf][nf] = __builtin_amdgcn_mfma_f32_16x16x32_bf16(
                    af[mf], bfr[nf], acc[mf][nf], 0, 0, 0);

        if (kt + 1 < NKT) writeA(xn, p ^ 1);   // after compute: X latency already paid
        p ^= 1;
    }

    // ---- epilogue: C/D layout col=lane&15, row=(lane>>4)*4+i (verified mapping) ----
    #pragma unroll
    for (int nf = 0; nf < 4; ++nf) {
        int col = wv * 64 + nf * 16 + c;
        float bv = bias[col];
        #pragma unroll
        for (int mf = 0; mf < 4; ++mf) {
            #pragma unroll
            for (int i = 0; i < 4; ++i) {
                int row = r0 + mf * 16 + q * 4 + i;
                Y[(size_t)row * D_OUT + col] = acc[mf][nf][i] + bv;
            }
        }
    }
}

extern "C" void kernel_launch(void* const* d_in, const int* in_sizes, int n_in,
                              void* d_out, int out_size, void* d_ws, size_t ws_size,
                              hipStream_t stream) {
    const float* X    = (const float*)d_in[0];
    const float* W    = (const float*)d_in[1];
    const float* bias = (const float*)d_in[2];
    float* Y          = (float*)d_out;
    unsigned short* wsb = (unsigned short*)d_ws;   // 512 KB bf16 k-tiled W^T copy

    (void)hipFuncSetAttribute((const void*)sparse_dense_gemm,
                              hipFuncAttributeMaxDynamicSharedMemorySize, LDS_BYTES);

    convert_w<<<1024, 256, 0, stream>>>(W, wsb);
    sparse_dense_gemm<<<N_ROWS / BM, THREADS, LDS_BYTES, stream>>>(X, wsb, bias, Y);
}